// Round 2
// baseline (847.608 us; speedup 1.0000x reference)
//
#include <hip/hip_runtime.h>
#include <stdint.h>

#define NROWS 500000
#define FDIM 132
#define NTILES 7813          // ceil(500000/64)
#define GRID 768             // 3 blocks/CU * 256 CU
// D_IN = 136, M_TOT = 24, segments start {0,3,8,15} len {3,5,7,9}

typedef unsigned short u16;
typedef unsigned int   u32;

typedef __attribute__((ext_vector_type(8))) u16    us8;
typedef __attribute__((ext_vector_type(8))) __bf16 bf16x8;
typedef __attribute__((ext_vector_type(4))) float  f32x4;

typedef __attribute__((address_space(1))) const void* as1_cvp;
typedef __attribute__((address_space(3))) void*       as3_vp;

__device__ __forceinline__ u16 f2bf(float f) {
    u32 u = __builtin_bit_cast(u32, f);
    u = u + 0x7FFFu + ((u >> 16) & 1u);   // RNE
    return (u16)(u >> 16);
}

#define BAR_FULL() asm volatile("s_waitcnt vmcnt(0) lgkmcnt(0)\n\ts_barrier" ::: "memory")
#define BAR_LDS()  asm volatile("s_waitcnt lgkmcnt(0)\n\ts_barrier" ::: "memory")

// ---- pre-kernel: W (f32 [136][136], row=k) -> wt bf16 [144][128] (row=n, col=k), zero-padded ----
__global__ __launch_bounds__(256) void wconv_kernel(const float* __restrict__ W,
                                                    u16* __restrict__ wt) {
    int id = blockIdx.x * 256 + threadIdx.x;     // 144*128 = 18432, grid=72
    int n = id >> 7, k = id & 127;
    float v = (n < 136) ? W[k * 136 + n] : 0.0f;
    wt[id] = f2bf(v);
}

// ---- main persistent kernel ----
__global__ __launch_bounds__(256, 3) void exch_kernel(const float* __restrict__ x,
                                                      const float* __restrict__ ev,
                                                      const float* __restrict__ W,
                                                      const float* __restrict__ b,
                                                      const u16* __restrict__ wt,
                                                      float* __restrict__ out) {
    // LDS total = 33792 + 12288 + 4352 + 544 + 1024 + 1024 + 1024 = 54048 B  (3 blocks/CU)
    __shared__ __align__(16) float A_sh[64 * 132];     // f32 x tile (DMA, contiguous)
    __shared__ __align__(16) float ev_sh[2][64 * 24];  // f32, double-buffered (DMA)
    __shared__ __align__(16) float Wtl_sh[8 * 136];    // f32 W rows k=128..135
    __shared__ __align__(16) float b_sh[136];
    __shared__ __align__(16) float xt_sh[64 * 4];      // f32 x[:,128..132) (copied from A_sh)
    __shared__ __align__(16) float contr_sh[64 * 4];
    __shared__ __align__(16) float cev_sh[64 * 4];

    const int tid   = threadIdx.x;
    const int lane  = tid & 63;
    const int w     = tid >> 6;        // wave 0..3
    const int c     = w & 1;           // col half: 0 -> tiles 0..4, 1 -> tiles 5..8
    const int rbase = (w >> 1) * 32;   // row half
    const int ln    = lane & 15;
    const int q     = lane >> 4;
    const int tbase = c ? 5 : 0;

    // ---- one-time init: Wtl + b into LDS ----
    for (int c0 = tid; c0 < 272; c0 += 256)
        *(f32x4*)(&Wtl_sh[c0 * 4]) = *(const f32x4*)(W + 128 * 136 + c0 * 4);
    if (tid < 34)
        *(f32x4*)(&b_sh[tid * 4]) = *(const f32x4*)(b + tid * 4);

    // ---- DMA helper (as lambda): stage tile's x (f32) + ev (f32) ----
    auto dma_tile = [&](int tile, int pbuf) {
        int row0 = tile * 64;
        int vr   = NROWS - row0; if (vr > 64) vr = 64;
        int vbA  = vr * 528;   // bytes of valid x
        int vbE  = vr * 96;    // bytes of valid ev
        const char* xg = (const char*)(x + (size_t)row0 * FDIM);
        const char* eg = (const char*)(ev + (size_t)row0 * 24);
        char* Ab = (char*)A_sh;
        char* Eb = (char*)ev_sh[pbuf];
#pragma unroll
        for (int ii = 0; ii < 9; ++ii) {           // 33 chunks of 1024 B over 4 waves
            int i = w + ii * 4;
            if (i < 33) {
                int off = i * 1024 + lane * 16;
                if (off + 16 <= vbA)
                    __builtin_amdgcn_global_load_lds((as1_cvp)(xg + off),
                                                     (as3_vp)(Ab + i * 1024), 16, 0, 0);
            }
        }
#pragma unroll
        for (int ii = 0; ii < 2; ++ii) {           // 6 chunks of 1024 B
            int i = w + ii * 4;
            if (i < 6) {
                int off = i * 1024 + lane * 16;
                if (off + 16 <= vbE)
                    __builtin_amdgcn_global_load_lds((as1_cvp)(eg + off),
                                                     (as3_vp)(Eb + i * 1024), 16, 0, 0);
            }
        }
    };

    int p = 0;
    dma_tile(blockIdx.x, 0);   // prologue DMA for first tile

    for (int tile = blockIdx.x; tile < NTILES; tile += GRID) {
        const int row0 = tile * 64;
        const float* evp = ev_sh[p];

        BAR_FULL();   // S1: DMA complete (each wave drains own vmcnt), LDS init visible

        // ---- phase1a: contr (one thread per (row,seg)) + x-tail copy ----
        {
            int r = tid >> 2, d = tid & 3;
            int st = d * (d + 2);       // 0,3,8,15
            int len = 2 * d + 3;        // 3,5,7,9
            float s = 0.f;
            for (int j = 0; j < len; ++j) {
                float v = evp[r * 24 + st + j];
                s += v * v;
            }
            contr_sh[r * 4 + d] = s;
            xt_sh[tid] = A_sh[r * FDIM + 128 + d];
        }

        // ---- phase1b: MFMA.  B-frags from global wt (L2-hot), A from LDS f32 -> bf16 ----
        f32x4 acc[2][5];
#pragma unroll
        for (int s2 = 0; s2 < 2; ++s2)
#pragma unroll
            for (int i = 0; i < 5; ++i) acc[s2][i] = (f32x4){0.f, 0.f, 0.f, 0.f};

#pragma unroll
        for (int kc = 0; kc < 4; ++kc) {
            us8 bf[5];
#pragma unroll
            for (int i = 0; i < 5; ++i) {
                int t = tbase + i;
                if (t < 9)
                    bf[i] = *(const us8*)(wt + (size_t)(t * 16 + ln) * 128 + kc * 32 + q * 8);
            }
#pragma unroll
            for (int sub = 0; sub < 2; ++sub) {
                const float* ap = &A_sh[(rbase + sub * 16 + ln) * FDIM + kc * 32 + q * 8];
                f32x4 a0 = *(const f32x4*)ap;
                f32x4 a1 = *(const f32x4*)(ap + 4);
                us8 av;
                av[0] = f2bf(a0[0]); av[1] = f2bf(a0[1]); av[2] = f2bf(a0[2]); av[3] = f2bf(a0[3]);
                av[4] = f2bf(a1[0]); av[5] = f2bf(a1[1]); av[6] = f2bf(a1[2]); av[7] = f2bf(a1[3]);
                bf16x8 a16 = __builtin_bit_cast(bf16x8, av);
#pragma unroll
                for (int i = 0; i < 5; ++i) {
                    int t = tbase + i;
                    if (t < 9)
                        acc[sub][i] = __builtin_amdgcn_mfma_f32_16x16x32_bf16(
                            a16, __builtin_bit_cast(bf16x8, bf[i]), acc[sub][i], 0, 0, 0);
                }
            }
        }

        BAR_LDS();    // S2: contr/xt visible; all A_sh/ev-contr reads done

        // ---- issue next tile's DMA NOW (stays in flight through the epilogue) ----
        {
            int nxt = tile + GRID;
            if (nxt < NTILES) dma_tile(nxt, p ^ 1);
        }

        // ---- epilogue A+B: exact fp32 tail, store cx, stash cev ----
        float wt8v[5][8], biasv[5];
#pragma unroll
        for (int i = 0; i < 5; ++i) {
            int t = tbase + i;
            int col = t * 16 + ln;
            if (t < 9 && col < 136) {
#pragma unroll
                for (int j = 0; j < 8; ++j) wt8v[i][j] = Wtl_sh[j * 136 + col];
                biasv[i] = b_sh[col];
            } else {
#pragma unroll
                for (int j = 0; j < 8; ++j) wt8v[i][j] = 0.f;
                biasv[i] = 0.f;
            }
        }
#pragma unroll
        for (int sub = 0; sub < 2; ++sub) {
            f32x4 xr[4], cr[4];
#pragma unroll
            for (int r = 0; r < 4; ++r) {
                int row = rbase + sub * 16 + q * 4 + r;
                xr[r] = *(const f32x4*)(&xt_sh[row * 4]);
                cr[r] = *(const f32x4*)(&contr_sh[row * 4]);
            }
#pragma unroll
            for (int i = 0; i < 5; ++i) {
                int t = tbase + i;
                if (t >= 9) continue;
                int col = t * 16 + ln;
#pragma unroll
                for (int r = 0; r < 4; ++r) {
                    int row  = rbase + sub * 16 + q * 4 + r;
                    int grow = row0 + row;
                    float y = acc[sub][i][r] + biasv[i];
                    y += xr[r][0] * wt8v[i][0] + xr[r][1] * wt8v[i][1]
                       + xr[r][2] * wt8v[i][2] + xr[r][3] * wt8v[i][3];
                    y += cr[r][0] * wt8v[i][4] + cr[r][1] * wt8v[i][5]
                       + cr[r][2] * wt8v[i][6] + cr[r][3] * wt8v[i][7];
                    if (col < FDIM) {
                        if (grow < NROWS) out[(size_t)grow * FDIM + col] = y;
                    } else if (col < 136) {
                        cev_sh[row * 4 + (col - FDIM)] = y;
                    }
                }
            }
        }

        BAR_LDS();    // S3: cev visible (vmcnt NOT drained — DMA keeps flying)

        // ---- epilogue C: out1[n,m] = cev[n,seg(m)] * ev[n,m] ----
#pragma unroll
        for (int i2 = 0; i2 < 2; ++i2) {
            int cix = tid + i2 * 256;
            if (cix < 384) {
                int row = cix / 6, j4 = cix % 6;
                int grow = row0 + row;
                if (grow < NROWS) {
                    f32x4 e = *(const f32x4*)(&evp[row * 24 + j4 * 4]);
                    f32x4 o;
#pragma unroll
                    for (int u = 0; u < 4; ++u) {
                        int m = j4 * 4 + u;
                        int d = (m < 3) ? 0 : (m < 8) ? 1 : (m < 15) ? 2 : 3;
                        o[u] = cev_sh[row * 4 + d] * e[u];
                    }
                    *(f32x4*)(out + (size_t)NROWS * FDIM + (size_t)grow * 24 + j4 * 4) = o;
                }
            }
        }

        p ^= 1;
    }
}

extern "C" void kernel_launch(void* const* d_in, const int* in_sizes, int n_in,
                              void* d_out, int out_size, void* d_ws, size_t ws_size,
                              hipStream_t stream) {
    const float* x  = (const float*)d_in[0];
    const float* ev = (const float*)d_in[1];
    const float* W  = (const float*)d_in[2];
    const float* b  = (const float*)d_in[3];
    u16* wt = (u16*)d_ws;   // 36864 B

    wconv_kernel<<<72, 256, 0, stream>>>(W, wt);
    exch_kernel<<<GRID, 256, 0, stream>>>(x, ev, W, b, wt, (float*)d_out);
}